// Round 6
// baseline (1547.754 us; speedup 1.0000x reference)
//
#include <hip/hip_runtime.h>
#include <stdint.h>
#include <stddef.h>

#define B_DIM 2048
#define FIN   4096
#define FOUT  2048
#define NITER 10
#define SMIN  1e-5f

typedef float floatx16 __attribute__((ext_vector_type(16)));
typedef short bf16x8   __attribute__((ext_vector_type(8)));

__device__ inline unsigned short f2bf(float f) {
    unsigned int u = __float_as_uint(f);
    u += 0x7fffu + ((u >> 16) & 1u);
    return (unsigned short)(u >> 16);
}
__device__ inline float bflo(unsigned int u) { return __uint_as_float(u << 16); }
__device__ inline float bfhi(unsigned int u) { return __uint_as_float(u & 0xffff0000u); }
__device__ inline unsigned int pack2(float a, float b) {
    return (unsigned int)f2bf(a) | ((unsigned int)f2bf(b) << 16);
}

__device__ inline void async16(const void* g, void* l) {
    __builtin_amdgcn_global_load_lds(
        (const __attribute__((address_space(1))) void*)g,
        (__attribute__((address_space(3))) void*)l, 16, 0, 0);
}

__device__ inline float block_row_sum(float v) {
    #pragma unroll
    for (int o = 32; o > 0; o >>= 1) v += __shfl_down(v, o, 64);
    __shared__ float red[4];
    const int lane = threadIdx.x & 63, w = threadIdx.x >> 6;
    if (lane == 0) red[w] = v;
    __syncthreads();
    return red[0] + red[1] + red[2] + red[3];
}

// Wn = clip(W,1e-5)/rowsum -> bf16 (FOUT x FIN)
__global__ __launch_bounds__(256) void k_norm_w(const float* __restrict__ W,
                                                unsigned short* __restrict__ Wn) {
    const int row = blockIdx.x;
    const float4* src = (const float4*)(W + (size_t)row * FIN);
    float4 vals[4];
    float s = 0.f;
    #pragma unroll
    for (int i = 0; i < 4; ++i) {
        float4 v = src[i * 256 + threadIdx.x];
        v.x = fmaxf(v.x, SMIN); v.y = fmaxf(v.y, SMIN);
        v.z = fmaxf(v.z, SMIN); v.w = fmaxf(v.w, SMIN);
        vals[i] = v;
        s += (v.x + v.y) + (v.z + v.w);
    }
    s = block_row_sum(s);
    const float inv = 1.f / fmaxf(s, 1e-20f);
    ushort4* dst = (ushort4*)(Wn + (size_t)row * FIN);
    #pragma unroll
    for (int i = 0; i < 4; ++i) {
        float4 v = vals[i];
        ushort4 o;
        o.x = f2bf(v.x * inv); o.y = f2bf(v.y * inv);
        o.z = f2bf(v.z * inv); o.w = f2bf(v.w * inv);
        dst[i * 256 + threadIdx.x] = o;
    }
}

// xn = x / rowsum(x) -> bf16 packed (B x FIN)
__global__ __launch_bounds__(256) void k_norm_x(const float* __restrict__ x,
                                                unsigned int* __restrict__ xnb) {
    const int row = blockIdx.x;
    const float4* src = (const float4*)(x + (size_t)row * FIN);
    float4 vals[4];
    float s = 0.f;
    #pragma unroll
    for (int j = 0; j < 2; ++j) {
        const int idx = j * 256 + threadIdx.x;
        float4 a = src[2 * idx], b = src[2 * idx + 1];
        vals[2 * j] = a; vals[2 * j + 1] = b;
        s += (fabsf(a.x) + fabsf(a.y)) + (fabsf(a.z) + fabsf(a.w));
        s += (fabsf(b.x) + fabsf(b.y)) + (fabsf(b.z) + fabsf(b.w));
    }
    s = block_row_sum(s);
    const float inv = 1.f / fmaxf(s, 1e-20f);
    uint4* dst = (uint4*)(xnb + (size_t)row * (FIN / 2));
    #pragma unroll
    for (int j = 0; j < 2; ++j) {
        float4 a = vals[2 * j], b = vals[2 * j + 1];
        uint4 o;
        o.x = pack2(a.x * inv, a.y * inv);
        o.y = pack2(a.z * inv, a.w * inv);
        o.z = pack2(b.x * inv, b.y * inv);
        o.w = pack2(b.z * inv, b.w * inv);
        dst[j * 256 + threadIdx.x] = o;
    }
}

// WnT[i][o] = Wn[o][i]  (bf16)
__global__ __launch_bounds__(256) void k_transpose(const unsigned short* __restrict__ src,
                                                   unsigned short* __restrict__ dst) {
    __shared__ unsigned short tile[32][33];
    const int bi = blockIdx.x * 32, bo = blockIdx.y * 32;
    const int tx = threadIdx.x, ty = threadIdx.y;  // (32,8)
    #pragma unroll
    for (int j = 0; j < 4; ++j)
        tile[ty + j * 8][tx] = src[(size_t)(bo + ty + j * 8) * FIN + bi + tx];
    __syncthreads();
    #pragma unroll
    for (int j = 0; j < 4; ++j)
        dst[(size_t)(bi + ty + j * 8) * FOUT + bo + tx] = tile[tx][ty + j * 8];
}

__global__ __launch_bounds__(256) void k_init_h(float* __restrict__ h,
                                                unsigned short* __restrict__ hb) {
    const int i = blockIdx.x * blockDim.x + threadIdx.x;
    const float hv = 1.f / (float)FOUT;
    float4 v; v.x = hv; v.y = hv; v.z = hv; v.w = hv;
    ((float4*)h)[i] = v;
    const unsigned short b = f2bf(hv);
    ushort4 u; u.x = b; u.y = b; u.z = b; u.w = b;
    ((ushort4*)hb)[i] = u;
}

// NT GEMM, split-K, 128x128 tile, BK=64, 4 waves each 64x64 = 2x2 of
// v_mfma_f32_32x32x16_bf16.
// LDS layout: K-major granules As[g][row][16 shorts], g = K-slice of 16
// (BK=64 -> 4 granules). Each fragment ds_read_b128 is then an exact
// permutation of a contiguous 1KB-aligned block (rows m0..m0+31 of one
// granule) -- the address-set shape of the measured-zero R3 config.
// 1-bit k-half swizzle (slot = half ^ ((row>>2)&1)) gives 2 touches/bank
// per 16-lane phase. R4/R5's strided read sets measured 4 cyc/b128.
template <int OUT_BF16>
__global__ __launch_bounds__(256) void k_gemm_nt(const unsigned short* __restrict__ A,
                                                 const unsigned short* __restrict__ Bm,
                                                 void* __restrict__ C,
                                                 int N, int K, int Ksub) {
    __shared__ __align__(16) unsigned short As[4 * 128 * 16];  // 16 KB
    __shared__ __align__(16) unsigned short Bs[4 * 128 * 16];  // 16 KB
    const int tid  = threadIdx.x;
    const int wave = tid >> 6;
    const int lane = tid & 63;
    const int bm = blockIdx.y * 128;
    const int bn = blockIdx.x * 128;
    const int kz = blockIdx.z * Ksub;
    const int wr = (wave >> 1) * 64;
    const int wc = (wave & 1) * 64;
    const int l31 = lane & 31;
    const int half = lane >> 5;

    floatx16 acc[2][2] = {};

    // staging: wave w covers rows [w*32, w*32+32). lane -> row = w*32+(lane>>1),
    // LDS k-half slot = lane&1 which must hold global k-half (lane&1)^((row>>2)&1).
    // LDS dest per instr: granule g slab base + lane*16B (contiguous 1KB).
    const int srow = wave * 32 + (lane >> 1);
    const int kh = (lane & 1) ^ ((srow >> 2) & 1);   // global k-half to fetch
    const unsigned short* ga = A  + (size_t)(bm + srow) * K + kh * 8;
    const unsigned short* gb = Bm + (size_t)(bn + srow) * K + kh * 8;

    for (int k0 = kz; k0 < kz + Ksub; k0 += 64) {
        __syncthreads();
        #pragma unroll
        for (int g = 0; g < 4; ++g) {
            async16(ga + k0 + g * 16, &As[g * 2048 + wave * 512]);
            async16(gb + k0 + g * 16, &Bs[g * 2048 + wave * 512]);
        }
        __syncthreads();

        const int sw = (l31 >> 2) & 1;   // (row>>2)&1: wr, t*32 are mult. of 32
        const int slot = (half ^ sw) * 8;
        #pragma unroll
        for (int kk = 0; kk < 4; ++kk) {
            bf16x8 af[2], bf[2];
            #pragma unroll
            for (int t = 0; t < 2; ++t) {
                af[t] = *(const bf16x8*)&As[kk * 2048 + (wr + t * 32 + l31) * 16 + slot];
                bf[t] = *(const bf16x8*)&Bs[kk * 2048 + (wc + t * 32 + l31) * 16 + slot];
            }
            #pragma unroll
            for (int mt = 0; mt < 2; ++mt)
                #pragma unroll
                for (int nt = 0; nt < 2; ++nt)
                    acc[mt][nt] = __builtin_amdgcn_mfma_f32_32x32x16_bf16(
                        af[mt], bf[nt], acc[mt][nt], 0, 0, 0);
        }
    }

    // C/D (verified m74/m101): col = lane&31, row = (reg&3)+8*(reg>>2)+4*(lane>>5)
    const int row0 = 4 * half;
    #pragma unroll
    for (int mt = 0; mt < 2; ++mt) {
        #pragma unroll
        for (int nt = 0; nt < 2; ++nt) {
            #pragma unroll
            for (int reg = 0; reg < 16; ++reg) {
                const int rr = bm + wr + mt * 32 + row0 + (reg & 3) + 8 * (reg >> 2);
                const int cc = bn + wc + nt * 32 + l31;
                if (OUT_BF16) {
                    unsigned short* o = (unsigned short*)C + (size_t)blockIdx.z * B_DIM * N;
                    o[(size_t)rr * N + cc] = f2bf(acc[mt][nt][reg]);
                } else {
                    float* o = (float*)C + (size_t)blockIdx.z * B_DIM * N;
                    o[(size_t)rr * N + cc] = acc[mt][nt][reg];
                }
            }
        }
    }
}

// recon = sum of bf16 partials; s = rowsum(clip); r = xn*s/clip -> bf16
__global__ __launch_bounds__(256) void k_make_ratio(const unsigned short* __restrict__ rec,
                                                    int nparts,
                                                    const unsigned int* __restrict__ xnb,
                                                    unsigned int* __restrict__ r) {
    const int row = blockIdx.x;
    float v[16];
    float s = 0.f;
    #pragma unroll
    for (int g = 0; g < 2; ++g) {
        const int idx = g * 256 + threadIdx.x;
        uint4 u = ((const uint4*)(rec + (size_t)row * FIN))[idx];
        float* p = v + g * 8;
        p[0] = bflo(u.x); p[1] = bfhi(u.x); p[2] = bflo(u.y); p[3] = bfhi(u.y);
        p[4] = bflo(u.z); p[5] = bfhi(u.z); p[6] = bflo(u.w); p[7] = bfhi(u.w);
        for (int z = 1; z < nparts; ++z) {
            uint4 q = ((const uint4*)(rec + (size_t)z * B_DIM * FIN + (size_t)row * FIN))[idx];
            p[0] += bflo(q.x); p[1] += bfhi(q.x); p[2] += bflo(q.y); p[3] += bfhi(q.y);
            p[4] += bflo(q.z); p[5] += bfhi(q.z); p[6] += bflo(q.w); p[7] += bfhi(q.w);
        }
        #pragma unroll
        for (int e = 0; e < 8; ++e) { p[e] = fmaxf(p[e], SMIN); s += p[e]; }
    }
    s = block_row_sum(s);
    #pragma unroll
    for (int g = 0; g < 2; ++g) {
        const int idx = g * 256 + threadIdx.x;
        uint4 xu = ((const uint4*)(xnb + (size_t)row * (FIN / 2)))[idx];
        float* p = v + g * 8;
        uint4 o;
        o.x = pack2(bflo(xu.x) * s / p[0], bfhi(xu.x) * s / p[1]);
        o.y = pack2(bflo(xu.y) * s / p[2], bfhi(xu.y) * s / p[3]);
        o.z = pack2(bflo(xu.z) * s / p[4], bfhi(xu.z) * s / p[5]);
        o.w = pack2(bflo(xu.w) * s / p[6], bfhi(xu.w) * s / p[7]);
        ((uint4*)(r + (size_t)row * (FIN / 2)))[idx] = o;
    }
}

// upd = sum fp32 partials; t = clip(h*upd); h' = t/rowsum(t); fp32 + bf16 out
__global__ __launch_bounds__(256) void k_update_h(const float* __restrict__ hin,
                                                  const float* __restrict__ upd,
                                                  int nparts,
                                                  float* __restrict__ hout,
                                                  unsigned short* __restrict__ hbf) {
    const int row = blockIdx.x;
    const float4* hp = (const float4*)(hin + (size_t)row * FOUT);
    float4 vals[2];
    float s = 0.f;
    #pragma unroll
    for (int i = 0; i < 2; ++i) {
        const int idx = i * 256 + threadIdx.x;
        float4 hv = hp[idx];
        float4 uv = ((const float4*)(upd + (size_t)row * FOUT))[idx];
        for (int z = 1; z < nparts; ++z) {
            float4 p = ((const float4*)(upd + (size_t)z * B_DIM * FOUT + (size_t)row * FOUT))[idx];
            uv.x += p.x; uv.y += p.y; uv.z += p.z; uv.w += p.w;
        }
        float4 v;
        v.x = fmaxf(hv.x * uv.x, SMIN);
        v.y = fmaxf(hv.y * uv.y, SMIN);
        v.z = fmaxf(hv.z * uv.z, SMIN);
        v.w = fmaxf(hv.w * uv.w, SMIN);
        vals[i] = v;
        s += (v.x + v.y) + (v.z + v.w);
    }
    s = block_row_sum(s);
    const float inv = 1.f / fmaxf(s, 1e-20f);
    float4* op = (float4*)(hout + (size_t)row * FOUT);
    ushort4* bp = (ushort4*)(hbf + (size_t)row * FOUT);
    #pragma unroll
    for (int i = 0; i < 2; ++i) {
        float4 v = vals[i];
        v.x *= inv; v.y *= inv; v.z *= inv; v.w *= inv;
        op[i * 256 + threadIdx.x] = v;
        ushort4 o;
        o.x = f2bf(v.x); o.y = f2bf(v.y); o.z = f2bf(v.z); o.w = f2bf(v.w);
        bp[i * 256 + threadIdx.x] = o;
    }
}

extern "C" void kernel_launch(void* const* d_in, const int* in_sizes, int n_in,
                              void* d_out, int out_size, void* d_ws, size_t ws_size,
                              hipStream_t stream) {
    const float* x = (const float*)d_in[0];
    const float* W = (const float*)d_in[1];
    float* out = (float*)d_out;

    const size_t RECON_PART = (size_t)B_DIM * FIN * 2;   // bf16, 16.78 MB
    const size_t UPD_PART   = (size_t)B_DIM * FOUT * 4;  // fp32, 16.78 MB
    const size_t FIXED      = 93000000;                  // non-partial buffers
    int S1 = 1, S2 = 1;
    if (ws_size >= FIXED + 2 * RECON_PART + 4 * UPD_PART + (1 << 20)) {
        S1 = 2; S2 = 4;
    }

    char* ws = (char*)d_ws;
    size_t off = 0;
    auto alloc = [&](size_t bytes) {
        void* p = ws + off;
        off += (bytes + 255) & ~(size_t)255;
        return p;
    };
    unsigned short* Wn  = (unsigned short*)alloc((size_t)FOUT * FIN * 2);
    unsigned short* WnT = (unsigned short*)alloc((size_t)FIN * FOUT * 2);
    unsigned short* hbf = (unsigned short*)alloc((size_t)B_DIM * FOUT * 2);
    unsigned int*   rbf = (unsigned int*)alloc((size_t)B_DIM * FIN * 2);
    unsigned int*   xnb = (unsigned int*)alloc((size_t)B_DIM * FIN * 2);
    float* h            = (float*)alloc((size_t)B_DIM * FOUT * 4);
    unsigned short* rec = (unsigned short*)alloc(RECON_PART * S1);
    float* upd          = (float*)alloc(UPD_PART * S2);
    (void)in_sizes; (void)n_in; (void)out_size;

    k_norm_w<<<FOUT, 256, 0, stream>>>(W, Wn);
    k_transpose<<<dim3(FIN / 32, FOUT / 32), dim3(32, 8), 0, stream>>>(Wn, WnT);
    k_norm_x<<<B_DIM, 256, 0, stream>>>(x, xnb);
    k_init_h<<<(B_DIM * FOUT) / (256 * 4), 256, 0, stream>>>(h, hbf);

    for (int it = 0; it < NITER; ++it) {
        // recon = h @ Wn : NT A=hbf (K=FOUT), B=WnT (FIN x FOUT), bf16 partials
        k_gemm_nt<1><<<dim3(FIN / 128, B_DIM / 128, S1), 256, 0, stream>>>(
            hbf, WnT, rec, FIN, FOUT, FOUT / S1);
        k_make_ratio<<<B_DIM, 256, 0, stream>>>(rec, S1, xnb, rbf);
        // upd = r @ Wn^T : NT A=rbf (K=FIN), B=Wn (FOUT x FIN), fp32 partials
        k_gemm_nt<0><<<dim3(FOUT / 128, B_DIM / 128, S2), 256, 0, stream>>>(
            (const unsigned short*)rbf, Wn, upd, FOUT, FIN, FIN / S2);
        k_update_h<<<B_DIM, 256, 0, stream>>>(h, upd, S2, (it == NITER - 1) ? out : h, hbf);
    }
}

// Round 7
// 1327.378 us; speedup vs baseline: 1.1660x; 1.1660x over previous
//
#include <hip/hip_runtime.h>
#include <stdint.h>
#include <stddef.h>

#define B_DIM 2048
#define FIN   4096
#define FOUT  2048
#define NITER 10
#define SMIN  1e-5f

typedef float floatx16 __attribute__((ext_vector_type(16)));
typedef short bf16x8   __attribute__((ext_vector_type(8)));

__device__ inline unsigned short f2bf(float f) {
    unsigned int u = __float_as_uint(f);
    u += 0x7fffu + ((u >> 16) & 1u);
    return (unsigned short)(u >> 16);
}
__device__ inline float bflo(unsigned int u) { return __uint_as_float(u << 16); }
__device__ inline float bfhi(unsigned int u) { return __uint_as_float(u & 0xffff0000u); }
__device__ inline unsigned int pack2(float a, float b) {
    return (unsigned int)f2bf(a) | ((unsigned int)f2bf(b) << 16);
}

__device__ inline void async16(const void* g, void* l) {
    __builtin_amdgcn_global_load_lds(
        (const __attribute__((address_space(1))) void*)g,
        (__attribute__((address_space(3))) void*)l, 16, 0, 0);
}

__device__ inline float block_row_sum(float v) {
    #pragma unroll
    for (int o = 32; o > 0; o >>= 1) v += __shfl_down(v, o, 64);
    __shared__ float red[4];
    const int lane = threadIdx.x & 63, w = threadIdx.x >> 6;
    if (lane == 0) red[w] = v;
    __syncthreads();
    return red[0] + red[1] + red[2] + red[3];
}

// Wn = clip(W,1e-5)/rowsum -> bf16 (FOUT x FIN)
__global__ __launch_bounds__(256) void k_norm_w(const float* __restrict__ W,
                                                unsigned short* __restrict__ Wn) {
    const int row = blockIdx.x;
    const float4* src = (const float4*)(W + (size_t)row * FIN);
    float4 vals[4];
    float s = 0.f;
    #pragma unroll
    for (int i = 0; i < 4; ++i) {
        float4 v = src[i * 256 + threadIdx.x];
        v.x = fmaxf(v.x, SMIN); v.y = fmaxf(v.y, SMIN);
        v.z = fmaxf(v.z, SMIN); v.w = fmaxf(v.w, SMIN);
        vals[i] = v;
        s += (v.x + v.y) + (v.z + v.w);
    }
    s = block_row_sum(s);
    const float inv = 1.f / fmaxf(s, 1e-20f);
    ushort4* dst = (ushort4*)(Wn + (size_t)row * FIN);
    #pragma unroll
    for (int i = 0; i < 4; ++i) {
        float4 v = vals[i];
        ushort4 o;
        o.x = f2bf(v.x * inv); o.y = f2bf(v.y * inv);
        o.z = f2bf(v.z * inv); o.w = f2bf(v.w * inv);
        dst[i * 256 + threadIdx.x] = o;
    }
}

// xn = x / rowsum(x) -> bf16 packed (B x FIN)
__global__ __launch_bounds__(256) void k_norm_x(const float* __restrict__ x,
                                                unsigned int* __restrict__ xnb) {
    const int row = blockIdx.x;
    const float4* src = (const float4*)(x + (size_t)row * FIN);
    float4 vals[4];
    float s = 0.f;
    #pragma unroll
    for (int j = 0; j < 2; ++j) {
        const int idx = j * 256 + threadIdx.x;
        float4 a = src[2 * idx], b = src[2 * idx + 1];
        vals[2 * j] = a; vals[2 * j + 1] = b;
        s += (fabsf(a.x) + fabsf(a.y)) + (fabsf(a.z) + fabsf(a.w));
        s += (fabsf(b.x) + fabsf(b.y)) + (fabsf(b.z) + fabsf(b.w));
    }
    s = block_row_sum(s);
    const float inv = 1.f / fmaxf(s, 1e-20f);
    uint4* dst = (uint4*)(xnb + (size_t)row * (FIN / 2));
    #pragma unroll
    for (int j = 0; j < 2; ++j) {
        float4 a = vals[2 * j], b = vals[2 * j + 1];
        uint4 o;
        o.x = pack2(a.x * inv, a.y * inv);
        o.y = pack2(a.z * inv, a.w * inv);
        o.z = pack2(b.x * inv, b.y * inv);
        o.w = pack2(b.z * inv, b.w * inv);
        dst[j * 256 + threadIdx.x] = o;
    }
}

// WnT[i][o] = Wn[o][i]  (bf16)
__global__ __launch_bounds__(256) void k_transpose(const unsigned short* __restrict__ src,
                                                   unsigned short* __restrict__ dst) {
    __shared__ unsigned short tile[32][33];
    const int bi = blockIdx.x * 32, bo = blockIdx.y * 32;
    const int tx = threadIdx.x, ty = threadIdx.y;  // (32,8)
    #pragma unroll
    for (int j = 0; j < 4; ++j)
        tile[ty + j * 8][tx] = src[(size_t)(bo + ty + j * 8) * FIN + bi + tx];
    __syncthreads();
    #pragma unroll
    for (int j = 0; j < 4; ++j)
        dst[(size_t)(bi + ty + j * 8) * FOUT + bo + tx] = tile[tx][ty + j * 8];
}

__global__ __launch_bounds__(256) void k_init_h(float* __restrict__ h,
                                                unsigned short* __restrict__ hb) {
    const int i = blockIdx.x * blockDim.x + threadIdx.x;
    const float hv = 1.f / (float)FOUT;
    float4 v; v.x = hv; v.y = hv; v.z = hv; v.w = hv;
    ((float4*)h)[i] = v;
    const unsigned short b = f2bf(hv);
    ushort4 u; u.x = b; u.y = b; u.z = b; u.w = b;
    ((ushort4*)hb)[i] = u;
}

// NT GEMM, split-K, 128x128 block tile, BK=64, TWO waves (128 threads),
// wave tile 128x64 = 4x2 of v_mfma_f32_32x32x16_bf16.
// Rationale (R6 post-mortem): 64x64 wave tile needs 4 b128 LDS reads per
// 4 MFMAs (12:8 cyc -> LDS-bound). 128x64 needs 6 per 8 (0.75/MFMA).
// LDS layout = R4's (fastest measured): 128x64 shorts row-major, chunk
// swizzle slot = chunk ^ (row&7). The 4 conflict-cyc/b128 counter is
// layout-invariant (R4/R5/R6) — treated as fixed cost, not chased.
template <int OUT_BF16>
__global__ __launch_bounds__(128) void k_gemm_nt(const unsigned short* __restrict__ A,
                                                 const unsigned short* __restrict__ Bm,
                                                 void* __restrict__ C,
                                                 int N, int K, int Ksub) {
    __shared__ __align__(16) unsigned short As[128 * 64];  // 16 KB
    __shared__ __align__(16) unsigned short Bs[128 * 64];  // 16 KB
    const int tid  = threadIdx.x;
    const int wave = tid >> 6;       // 0..1
    const int lane = tid & 63;
    const int bm = blockIdx.y * 128;
    const int bn = blockIdx.x * 128;
    const int kz = blockIdx.z * Ksub;
    const int wc = wave * 64;        // wave n-offset; wave covers all 128 m
    const int l31 = lane & 31;
    const int half = lane >> 5;

    floatx16 acc[4][2] = {};

    // staging: wave w loads rows [w*64, w*64+64) of each 128x64 tile,
    // 8 groups of 8 rows; lane -> row lr=lane>>3, slot=lane&7;
    // global k-chunk = slot ^ (lr&7) = slot ^ lr (lr<8).
    // LDS offset within group = lr*64 + slot*8 = lane*8 shorts = lane*16B.
    const int lr = lane >> 3;
    const int ks = ((lane & 7) ^ lr) * 8;   // shorts
    const unsigned short* ga = A  + (size_t)(bm + wave * 64 + lr) * K + ks;
    const unsigned short* gb = Bm + (size_t)(bn + wave * 64 + lr) * K + ks;

    for (int k0 = kz; k0 < kz + Ksub; k0 += 64) {
        __syncthreads();
        #pragma unroll
        for (int j = 0; j < 8; ++j) {
            // wave slab = 64 rows * 64 shorts = 4096; 8-row group = 512 shorts
            async16(ga + (size_t)j * 8 * K + k0, &As[wave * 4096 + j * 512]);
            async16(gb + (size_t)j * 8 * K + k0, &Bs[wave * 4096 + j * 512]);
        }
        __syncthreads();

        #pragma unroll
        for (int kk = 0; kk < 4; ++kk) {
            // frag row r = (t*32 + l31); k-chunk c = kk*2 + half lives at
            // slot c ^ (r&7); r&7 = l31&7 (t*32 multiple of 32)
            const int slot = ((kk * 2 + half) ^ (l31 & 7)) * 8;
            bf16x8 af[4], bf[2];
            #pragma unroll
            for (int t = 0; t < 4; ++t)
                af[t] = *(const bf16x8*)&As[(t * 32 + l31) * 64 + slot];
            #pragma unroll
            for (int t = 0; t < 2; ++t)
                bf[t] = *(const bf16x8*)&Bs[(wc + t * 32 + l31) * 64 + slot];
            #pragma unroll
            for (int mt = 0; mt < 4; ++mt)
                #pragma unroll
                for (int nt = 0; nt < 2; ++nt)
                    acc[mt][nt] = __builtin_amdgcn_mfma_f32_32x32x16_bf16(
                        af[mt], bf[nt], acc[mt][nt], 0, 0, 0);
        }
    }

    // C/D (verified m74/m101): col = lane&31, row = (reg&3)+8*(reg>>2)+4*(lane>>5)
    const int row0 = 4 * half;
    #pragma unroll
    for (int mt = 0; mt < 4; ++mt) {
        #pragma unroll
        for (int nt = 0; nt < 2; ++nt) {
            #pragma unroll
            for (int reg = 0; reg < 16; ++reg) {
                const int rr = bm + mt * 32 + row0 + (reg & 3) + 8 * (reg >> 2);
                const int cc = bn + wc + nt * 32 + l31;
                if (OUT_BF16) {
                    unsigned short* o = (unsigned short*)C + (size_t)blockIdx.z * B_DIM * N;
                    o[(size_t)rr * N + cc] = f2bf(acc[mt][nt][reg]);
                } else {
                    float* o = (float*)C + (size_t)blockIdx.z * B_DIM * N;
                    o[(size_t)rr * N + cc] = acc[mt][nt][reg];
                }
            }
        }
    }
}

// recon = sum of bf16 partials; s = rowsum(clip); r = xn*s/clip -> bf16
__global__ __launch_bounds__(256) void k_make_ratio(const unsigned short* __restrict__ rec,
                                                    int nparts,
                                                    const unsigned int* __restrict__ xnb,
                                                    unsigned int* __restrict__ r) {
    const int row = blockIdx.x;
    float v[16];
    float s = 0.f;
    #pragma unroll
    for (int g = 0; g < 2; ++g) {
        const int idx = g * 256 + threadIdx.x;
        uint4 u = ((const uint4*)(rec + (size_t)row * FIN))[idx];
        float* p = v + g * 8;
        p[0] = bflo(u.x); p[1] = bfhi(u.x); p[2] = bflo(u.y); p[3] = bfhi(u.y);
        p[4] = bflo(u.z); p[5] = bfhi(u.z); p[6] = bflo(u.w); p[7] = bfhi(u.w);
        for (int z = 1; z < nparts; ++z) {
            uint4 q = ((const uint4*)(rec + (size_t)z * B_DIM * FIN + (size_t)row * FIN))[idx];
            p[0] += bflo(q.x); p[1] += bfhi(q.x); p[2] += bflo(q.y); p[3] += bfhi(q.y);
            p[4] += bflo(q.z); p[5] += bfhi(q.z); p[6] += bflo(q.w); p[7] += bfhi(q.w);
        }
        #pragma unroll
        for (int e = 0; e < 8; ++e) { p[e] = fmaxf(p[e], SMIN); s += p[e]; }
    }
    s = block_row_sum(s);
    #pragma unroll
    for (int g = 0; g < 2; ++g) {
        const int idx = g * 256 + threadIdx.x;
        uint4 xu = ((const uint4*)(xnb + (size_t)row * (FIN / 2)))[idx];
        float* p = v + g * 8;
        uint4 o;
        o.x = pack2(bflo(xu.x) * s / p[0], bfhi(xu.x) * s / p[1]);
        o.y = pack2(bflo(xu.y) * s / p[2], bfhi(xu.y) * s / p[3]);
        o.z = pack2(bflo(xu.z) * s / p[4], bfhi(xu.z) * s / p[5]);
        o.w = pack2(bflo(xu.w) * s / p[6], bfhi(xu.w) * s / p[7]);
        ((uint4*)(r + (size_t)row * (FIN / 2)))[idx] = o;
    }
}

// upd = sum fp32 partials; t = clip(h*upd); h' = t/rowsum(t); fp32 + bf16 out
__global__ __launch_bounds__(256) void k_update_h(const float* __restrict__ hin,
                                                  const float* __restrict__ upd,
                                                  int nparts,
                                                  float* __restrict__ hout,
                                                  unsigned short* __restrict__ hbf) {
    const int row = blockIdx.x;
    const float4* hp = (const float4*)(hin + (size_t)row * FOUT);
    float4 vals[2];
    float s = 0.f;
    #pragma unroll
    for (int i = 0; i < 2; ++i) {
        const int idx = i * 256 + threadIdx.x;
        float4 hv = hp[idx];
        float4 uv = ((const float4*)(upd + (size_t)row * FOUT))[idx];
        for (int z = 1; z < nparts; ++z) {
            float4 p = ((const float4*)(upd + (size_t)z * B_DIM * FOUT + (size_t)row * FOUT))[idx];
            uv.x += p.x; uv.y += p.y; uv.z += p.z; uv.w += p.w;
        }
        float4 v;
        v.x = fmaxf(hv.x * uv.x, SMIN);
        v.y = fmaxf(hv.y * uv.y, SMIN);
        v.z = fmaxf(hv.z * uv.z, SMIN);
        v.w = fmaxf(hv.w * uv.w, SMIN);
        vals[i] = v;
        s += (v.x + v.y) + (v.z + v.w);
    }
    s = block_row_sum(s);
    const float inv = 1.f / fmaxf(s, 1e-20f);
    float4* op = (float4*)(hout + (size_t)row * FOUT);
    ushort4* bp = (ushort4*)(hbf + (size_t)row * FOUT);
    #pragma unroll
    for (int i = 0; i < 2; ++i) {
        float4 v = vals[i];
        v.x *= inv; v.y *= inv; v.z *= inv; v.w *= inv;
        op[i * 256 + threadIdx.x] = v;
        ushort4 o;
        o.x = f2bf(v.x); o.y = f2bf(v.y); o.z = f2bf(v.z); o.w = f2bf(v.w);
        bp[i * 256 + threadIdx.x] = o;
    }
}

extern "C" void kernel_launch(void* const* d_in, const int* in_sizes, int n_in,
                              void* d_out, int out_size, void* d_ws, size_t ws_size,
                              hipStream_t stream) {
    const float* x = (const float*)d_in[0];
    const float* W = (const float*)d_in[1];
    float* out = (float*)d_out;

    const size_t RECON_PART = (size_t)B_DIM * FIN * 2;   // bf16, 16.78 MB
    const size_t UPD_PART   = (size_t)B_DIM * FOUT * 4;  // fp32, 16.78 MB
    const size_t FIXED      = 93000000;                  // non-partial buffers
    int S1 = 1, S2 = 1;
    if (ws_size >= FIXED + 2 * RECON_PART + 4 * UPD_PART + (1 << 20)) {
        S1 = 2; S2 = 4;
    }

    char* ws = (char*)d_ws;
    size_t off = 0;
    auto alloc = [&](size_t bytes) {
        void* p = ws + off;
        off += (bytes + 255) & ~(size_t)255;
        return p;
    };
    unsigned short* Wn  = (unsigned short*)alloc((size_t)FOUT * FIN * 2);
    unsigned short* WnT = (unsigned short*)alloc((size_t)FIN * FOUT * 2);
    unsigned short* hbf = (unsigned short*)alloc((size_t)B_DIM * FOUT * 2);
    unsigned int*   rbf = (unsigned int*)alloc((size_t)B_DIM * FIN * 2);
    unsigned int*   xnb = (unsigned int*)alloc((size_t)B_DIM * FIN * 2);
    float* h            = (float*)alloc((size_t)B_DIM * FOUT * 4);
    unsigned short* rec = (unsigned short*)alloc(RECON_PART * S1);
    float* upd          = (float*)alloc(UPD_PART * S2);
    (void)in_sizes; (void)n_in; (void)out_size;

    k_norm_w<<<FOUT, 256, 0, stream>>>(W, Wn);
    k_transpose<<<dim3(FIN / 32, FOUT / 32), dim3(32, 8), 0, stream>>>(Wn, WnT);
    k_norm_x<<<B_DIM, 256, 0, stream>>>(x, xnb);
    k_init_h<<<(B_DIM * FOUT) / (256 * 4), 256, 0, stream>>>(h, hbf);

    for (int it = 0; it < NITER; ++it) {
        // recon = h @ Wn : NT A=hbf (K=FOUT), B=WnT (FIN x FOUT), bf16 partials
        k_gemm_nt<1><<<dim3(FIN / 128, B_DIM / 128, S1), 128, 0, stream>>>(
            hbf, WnT, rec, FIN, FOUT, FOUT / S1);
        k_make_ratio<<<B_DIM, 256, 0, stream>>>(rec, S1, xnb, rbf);
        // upd = r @ Wn^T : NT A=rbf (K=FIN), B=Wn (FOUT x FIN), fp32 partials
        k_gemm_nt<0><<<dim3(FOUT / 128, B_DIM / 128, S2), 128, 0, stream>>>(
            (const unsigned short*)rbf, Wn, upd, FOUT, FIN, FIN / S2);
        k_update_h<<<B_DIM, 256, 0, stream>>>(h, upd, S2, (it == NITER - 1) ? out : h, hbf);
    }
}

// Round 8
// 1212.864 us; speedup vs baseline: 1.2761x; 1.0944x over previous
//
#include <hip/hip_runtime.h>
#include <stdint.h>
#include <stddef.h>

#define B_DIM 2048
#define FIN   4096
#define FOUT  2048
#define NITER 10
#define SMIN  1e-5f

// fp8 pre-scales (exact powers of 2): Wn*2^14 <= ~17, h*2^8 <= 256 < 448 (e4m3 max)
#define WSCALE 16384.0f
#define HSCALE 256.0f
#define OUTSCALE (1.0f / 4194304.0f)   // 2^-22

typedef float floatx16 __attribute__((ext_vector_type(16)));
typedef short bf16x8   __attribute__((ext_vector_type(8)));

__device__ inline unsigned short f2bf(float f) {
    unsigned int u = __float_as_uint(f);
    u += 0x7fffu + ((u >> 16) & 1u);
    return (unsigned short)(u >> 16);
}
__device__ inline float bflo(unsigned int u) { return __uint_as_float(u << 16); }
__device__ inline float bfhi(unsigned int u) { return __uint_as_float(u & 0xffff0000u); }
__device__ inline unsigned int pack2(float a, float b) {
    return (unsigned int)f2bf(a) | ((unsigned int)f2bf(b) << 16);
}

__device__ inline void async16(const void* g, void* l) {
    __builtin_amdgcn_global_load_lds(
        (const __attribute__((address_space(1))) void*)g,
        (__attribute__((address_space(3))) void*)l, 16, 0, 0);
}

__device__ inline float block_row_sum(float v) {
    #pragma unroll
    for (int o = 32; o > 0; o >>= 1) v += __shfl_down(v, o, 64);
    __shared__ float red[4];
    const int lane = threadIdx.x & 63, w = threadIdx.x >> 6;
    if (lane == 0) red[w] = v;
    __syncthreads();
    return red[0] + red[1] + red[2] + red[3];
}

// Wn = clip(W,1e-5)/rowsum -> bf16 (FOUT x FIN)  [bf16 master, used by GEMM2 + fp8 transpose]
__global__ __launch_bounds__(256) void k_norm_w(const float* __restrict__ W,
                                                unsigned short* __restrict__ Wn) {
    const int row = blockIdx.x;
    const float4* src = (const float4*)(W + (size_t)row * FIN);
    float4 vals[4];
    float s = 0.f;
    #pragma unroll
    for (int i = 0; i < 4; ++i) {
        float4 v = src[i * 256 + threadIdx.x];
        v.x = fmaxf(v.x, SMIN); v.y = fmaxf(v.y, SMIN);
        v.z = fmaxf(v.z, SMIN); v.w = fmaxf(v.w, SMIN);
        vals[i] = v;
        s += (v.x + v.y) + (v.z + v.w);
    }
    s = block_row_sum(s);
    const float inv = 1.f / fmaxf(s, 1e-20f);
    ushort4* dst = (ushort4*)(Wn + (size_t)row * FIN);
    #pragma unroll
    for (int i = 0; i < 4; ++i) {
        float4 v = vals[i];
        ushort4 o;
        o.x = f2bf(v.x * inv); o.y = f2bf(v.y * inv);
        o.z = f2bf(v.z * inv); o.w = f2bf(v.w * inv);
        dst[i * 256 + threadIdx.x] = o;
    }
}

// xn = x / rowsum(x) -> bf16 packed (B x FIN)
__global__ __launch_bounds__(256) void k_norm_x(const float* __restrict__ x,
                                                unsigned int* __restrict__ xnb) {
    const int row = blockIdx.x;
    const float4* src = (const float4*)(x + (size_t)row * FIN);
    float4 vals[4];
    float s = 0.f;
    #pragma unroll
    for (int j = 0; j < 2; ++j) {
        const int idx = j * 256 + threadIdx.x;
        float4 a = src[2 * idx], b = src[2 * idx + 1];
        vals[2 * j] = a; vals[2 * j + 1] = b;
        s += (fabsf(a.x) + fabsf(a.y)) + (fabsf(a.z) + fabsf(a.w));
        s += (fabsf(b.x) + fabsf(b.y)) + (fabsf(b.z) + fabsf(b.w));
    }
    s = block_row_sum(s);
    const float inv = 1.f / fmaxf(s, 1e-20f);
    uint4* dst = (uint4*)(xnb + (size_t)row * (FIN / 2));
    #pragma unroll
    for (int j = 0; j < 2; ++j) {
        float4 a = vals[2 * j], b = vals[2 * j + 1];
        uint4 o;
        o.x = pack2(a.x * inv, a.y * inv);
        o.y = pack2(a.z * inv, a.w * inv);
        o.z = pack2(b.x * inv, b.y * inv);
        o.w = pack2(b.z * inv, b.w * inv);
        dst[j * 256 + threadIdx.x] = o;
    }
}

// WnT8[i][o] = fp8(Wn[o][i] * 2^14)   (B operand of GEMM1, fp8 e4m3)
__global__ __launch_bounds__(256) void k_transpose_fp8(const unsigned short* __restrict__ src,
                                                       unsigned char* __restrict__ dst) {
    __shared__ unsigned short tile[32][33];
    const int bi = blockIdx.x * 32, bo = blockIdx.y * 32;
    const int tx = threadIdx.x, ty = threadIdx.y;  // (32,8)
    #pragma unroll
    for (int j = 0; j < 4; ++j)
        tile[ty + j * 8][tx] = src[(size_t)(bo + ty + j * 8) * FIN + bi + tx];
    __syncthreads();
    #pragma unroll
    for (int j = 0; j < 4; ++j) {
        const float v = bflo((unsigned int)tile[tx][ty + j * 8]) * WSCALE;
        const unsigned int b = (unsigned int)__builtin_amdgcn_cvt_pk_fp8_f32(v, v, 0, false) & 0xffu;
        dst[(size_t)(bi + ty + j * 8) * FOUT + bo + tx] = (unsigned char)b;
    }
}

// h0 = 1/FOUT: fp32 master + fp8(h*2^8) = fp8(0.125) = 0x20 exactly
__global__ __launch_bounds__(256) void k_init_h(float* __restrict__ h,
                                                unsigned int* __restrict__ h8u) {
    const int i = blockIdx.x * blockDim.x + threadIdx.x;
    const float hv = 1.f / (float)FOUT;
    float4 v; v.x = hv; v.y = hv; v.z = hv; v.w = hv;
    ((float4*)h)[i] = v;
    h8u[i] = 0x20202020u;
}

// GEMM1 (fp8): rec_z = (h8 * WnT8^T) * 2^-22 -> bf16 partials.
// NT, split-K, 128x128 tile, BK=64, 4 waves each 64x64 = 2x2 of
// v_mfma_f32_32x32x16_fp8_fp8 (K=16, i64 operands = 8 fp8/lane, k=half*8+j).
// LDS 8 KB/operand; 16-B chunk swizzle slot = kc ^ ((row>>1)&3) (R3-verified
// form); fragment reads are ds_read_b64, 2 touches/bank (free per m136).
__global__ __launch_bounds__(256) void k_gemm_fp8(const unsigned char* __restrict__ A,
                                                  const unsigned char* __restrict__ Bm,
                                                  unsigned short* __restrict__ C,
                                                  int N, int K, int Ksub) {
    __shared__ __align__(16) unsigned char As[128 * 64];  // 8 KB
    __shared__ __align__(16) unsigned char Bs[128 * 64];  // 8 KB
    const int tid  = threadIdx.x;
    const int wave = tid >> 6;
    const int lane = tid & 63;
    const int bm = blockIdx.y * 128;
    const int bn = blockIdx.x * 128;
    const int kz = blockIdx.z * Ksub;
    const int wr = (wave >> 1) * 64;
    const int wc = (wave & 1) * 64;
    const int l31 = lane & 31;
    const int half = lane >> 5;

    floatx16 acc[2][2] = {};

    // staging: wave w covers rows [w*32,w*32+32) in 2 chunks of 16 rows.
    // lane -> row lr=lane>>2, slot=lane&3 (16-B units); global 16-B k-chunk
    // kc = slot ^ ((lr>>1)&3); LDS offset within chunk = lane*16 B.
    const int lr = lane >> 2;
    const int ks = ((lane & 3) ^ ((lane >> 3) & 3)) * 16;  // bytes
    const unsigned char* ga = A  + (size_t)(bm + wave * 32 + lr) * K + ks;
    const unsigned char* gb = Bm + (size_t)(bn + wave * 32 + lr) * K + ks;

    for (int k0 = kz; k0 < kz + Ksub; k0 += 64) {
        __syncthreads();
        #pragma unroll
        for (int j = 0; j < 2; ++j) {
            async16(ga + (size_t)j * 16 * K + k0, &As[wave * 2048 + j * 1024]);
            async16(gb + (size_t)j * 16 * K + k0, &Bs[wave * 2048 + j * 1024]);
        }
        __syncthreads();

        const int sw = (l31 >> 1) & 3;   // (row>>1)&3; wr/wc/t*32 are 0 mod 4 after >>1
        #pragma unroll
        for (int kk = 0; kk < 4; ++kk) {
            // chunk kk lives at slot kk^sw; lane's K=16 half at +half*8 bytes
            const int off = ((kk ^ sw) << 4) + (half << 3);
            long long af[2], bf[2];
            #pragma unroll
            for (int t = 0; t < 2; ++t) {
                af[t] = *(const long long*)&As[(wr + t * 32 + l31) * 64 + off];
                bf[t] = *(const long long*)&Bs[(wc + t * 32 + l31) * 64 + off];
            }
            #pragma unroll
            for (int mt = 0; mt < 2; ++mt)
                #pragma unroll
                for (int nt = 0; nt < 2; ++nt)
                    acc[mt][nt] = __builtin_amdgcn_mfma_f32_32x32x16_fp8_fp8(
                        af[mt], bf[nt], acc[mt][nt], 0, 0, 0);
        }
    }

    // C/D (verified m74/m101): col = lane&31, row = (reg&3)+8*(reg>>2)+4*(lane>>5)
    unsigned short* Cz = C + (size_t)blockIdx.z * B_DIM * N;
    const int row0 = 4 * half;
    #pragma unroll
    for (int mt = 0; mt < 2; ++mt) {
        #pragma unroll
        for (int nt = 0; nt < 2; ++nt) {
            #pragma unroll
            for (int reg = 0; reg < 16; ++reg) {
                const int rr = bm + wr + mt * 32 + row0 + (reg & 3) + 8 * (reg >> 2);
                const int cc = bn + wc + nt * 32 + l31;
                Cz[(size_t)rr * N + cc] = f2bf(acc[mt][nt][reg] * OUTSCALE);
            }
        }
    }
}

// GEMM2 (bf16, R4's best-measured config): upd_z = rbf * Wn^T, fp32 partials.
// 128x128 tile, BK=64, 4 waves each 64x64 = 2x2 of v_mfma_f32_32x32x16_bf16.
__global__ __launch_bounds__(256) void k_gemm_nt(const unsigned short* __restrict__ A,
                                                 const unsigned short* __restrict__ Bm,
                                                 float* __restrict__ C,
                                                 int N, int K, int Ksub) {
    __shared__ __align__(16) unsigned short As[128 * 64];  // 16 KB
    __shared__ __align__(16) unsigned short Bs[128 * 64];  // 16 KB
    const int tid  = threadIdx.x;
    const int wave = tid >> 6;
    const int lane = tid & 63;
    const int bm = blockIdx.y * 128;
    const int bn = blockIdx.x * 128;
    const int kz = blockIdx.z * Ksub;
    const int wr = (wave >> 1) * 64;
    const int wc = (wave & 1) * 64;
    const int l31 = lane & 31;
    const int half = lane >> 5;

    floatx16 acc[2][2] = {};

    const int lr = lane >> 3;
    const int ks = ((lane & 7) ^ lr) * 8;   // shorts
    const unsigned short* ga = A  + (size_t)(bm + wave * 32 + lr) * K + ks;
    const unsigned short* gb = Bm + (size_t)(bn + wave * 32 + lr) * K + ks;

    for (int k0 = kz; k0 < kz + Ksub; k0 += 64) {
        __syncthreads();
        #pragma unroll
        for (int j = 0; j < 4; ++j) {
            async16(ga + (size_t)j * 8 * K + k0, &As[wave * 2048 + j * 512]);
            async16(gb + (size_t)j * 8 * K + k0, &Bs[wave * 2048 + j * 512]);
        }
        __syncthreads();

        #pragma unroll
        for (int kk = 0; kk < 4; ++kk) {
            const int slot = ((kk * 2 + half) ^ (l31 & 7)) * 8;
            bf16x8 af[2], bf[2];
            #pragma unroll
            for (int t = 0; t < 2; ++t) {
                af[t] = *(const bf16x8*)&As[(wr + t * 32 + l31) * 64 + slot];
                bf[t] = *(const bf16x8*)&Bs[(wc + t * 32 + l31) * 64 + slot];
            }
            #pragma unroll
            for (int mt = 0; mt < 2; ++mt)
                #pragma unroll
                for (int nt = 0; nt < 2; ++nt)
                    acc[mt][nt] = __builtin_amdgcn_mfma_f32_32x32x16_bf16(
                        af[mt], bf[nt], acc[mt][nt], 0, 0, 0);
        }
    }

    float* Cz = C + (size_t)blockIdx.z * B_DIM * N;
    const int row0 = 4 * half;
    #pragma unroll
    for (int mt = 0; mt < 2; ++mt) {
        #pragma unroll
        for (int nt = 0; nt < 2; ++nt) {
            #pragma unroll
            for (int reg = 0; reg < 16; ++reg) {
                const int rr = bm + wr + mt * 32 + row0 + (reg & 3) + 8 * (reg >> 2);
                const int cc = bn + wc + nt * 32 + l31;
                Cz[(size_t)rr * N + cc] = acc[mt][nt][reg];
            }
        }
    }
}

// recon = sum of bf16 partials; s = rowsum(clip); r = xn*s/clip -> bf16
__global__ __launch_bounds__(256) void k_make_ratio(const unsigned short* __restrict__ rec,
                                                    int nparts,
                                                    const unsigned int* __restrict__ xnb,
                                                    unsigned int* __restrict__ r) {
    const int row = blockIdx.x;
    float v[16];
    float s = 0.f;
    #pragma unroll
    for (int g = 0; g < 2; ++g) {
        const int idx = g * 256 + threadIdx.x;
        uint4 u = ((const uint4*)(rec + (size_t)row * FIN))[idx];
        float* p = v + g * 8;
        p[0] = bflo(u.x); p[1] = bfhi(u.x); p[2] = bflo(u.y); p[3] = bfhi(u.y);
        p[4] = bflo(u.z); p[5] = bfhi(u.z); p[6] = bflo(u.w); p[7] = bfhi(u.w);
        for (int z = 1; z < nparts; ++z) {
            uint4 q = ((const uint4*)(rec + (size_t)z * B_DIM * FIN + (size_t)row * FIN))[idx];
            p[0] += bflo(q.x); p[1] += bfhi(q.x); p[2] += bflo(q.y); p[3] += bfhi(q.y);
            p[4] += bflo(q.z); p[5] += bfhi(q.z); p[6] += bflo(q.w); p[7] += bfhi(q.w);
        }
        #pragma unroll
        for (int e = 0; e < 8; ++e) { p[e] = fmaxf(p[e], SMIN); s += p[e]; }
    }
    s = block_row_sum(s);
    #pragma unroll
    for (int g = 0; g < 2; ++g) {
        const int idx = g * 256 + threadIdx.x;
        uint4 xu = ((const uint4*)(xnb + (size_t)row * (FIN / 2)))[idx];
        float* p = v + g * 8;
        uint4 o;
        o.x = pack2(bflo(xu.x) * s / p[0], bfhi(xu.x) * s / p[1]);
        o.y = pack2(bflo(xu.y) * s / p[2], bfhi(xu.y) * s / p[3]);
        o.z = pack2(bflo(xu.z) * s / p[4], bfhi(xu.z) * s / p[5]);
        o.w = pack2(bflo(xu.w) * s / p[6], bfhi(xu.w) * s / p[7]);
        ((uint4*)(r + (size_t)row * (FIN / 2)))[idx] = o;
    }
}

// upd = sum fp32 partials; t = clip(h*upd); h' = t/rowsum(t); fp32 master + fp8(h*2^8)
__global__ __launch_bounds__(256) void k_update_h(const float* __restrict__ hin,
                                                  const float* __restrict__ upd,
                                                  int nparts,
                                                  float* __restrict__ hout,
                                                  unsigned int* __restrict__ h8u) {
    const int row = blockIdx.x;
    const float4* hp = (const float4*)(hin + (size_t)row * FOUT);
    float4 vals[2];
    float s = 0.f;
    #pragma unroll
    for (int i = 0; i < 2; ++i) {
        const int idx = i * 256 + threadIdx.x;
        float4 hv = hp[idx];
        float4 uv = ((const float4*)(upd + (size_t)row * FOUT))[idx];
        for (int z = 1; z < nparts; ++z) {
            float4 p = ((const float4*)(upd + (size_t)z * B_DIM * FOUT + (size_t)row * FOUT))[idx];
            uv.x += p.x; uv.y += p.y; uv.z += p.z; uv.w += p.w;
        }
        float4 v;
        v.x = fmaxf(hv.x * uv.x, SMIN);
        v.y = fmaxf(hv.y * uv.y, SMIN);
        v.z = fmaxf(hv.z * uv.z, SMIN);
        v.w = fmaxf(hv.w * uv.w, SMIN);
        vals[i] = v;
        s += (v.x + v.y) + (v.z + v.w);
    }
    s = block_row_sum(s);
    const float inv = 1.f / fmaxf(s, 1e-20f);
    float4* op = (float4*)(hout + (size_t)row * FOUT);
    unsigned int* bp = h8u + (size_t)row * (FOUT / 4);
    #pragma unroll
    for (int i = 0; i < 2; ++i) {
        float4 v = vals[i];
        v.x *= inv; v.y *= inv; v.z *= inv; v.w *= inv;
        op[i * 256 + threadIdx.x] = v;
        unsigned int u = 0;
        u = (unsigned int)__builtin_amdgcn_cvt_pk_fp8_f32(v.x * HSCALE, v.y * HSCALE, (int)u, false);
        u = (unsigned int)__builtin_amdgcn_cvt_pk_fp8_f32(v.z * HSCALE, v.w * HSCALE, (int)u, true);
        bp[i * 256 + threadIdx.x] = u;
    }
}

extern "C" void kernel_launch(void* const* d_in, const int* in_sizes, int n_in,
                              void* d_out, int out_size, void* d_ws, size_t ws_size,
                              hipStream_t stream) {
    const float* x = (const float*)d_in[0];
    const float* W = (const float*)d_in[1];
    float* out = (float*)d_out;

    const size_t RECON_PART = (size_t)B_DIM * FIN * 2;   // bf16, 16.78 MB
    const size_t UPD_PART   = (size_t)B_DIM * FOUT * 4;  // fp32, 16.78 MB
    const size_t FIXED      = 81000000;                  // non-partial buffers (~80 MB)
    int S1 = 1, S2 = 1;
    if (ws_size >= FIXED + 2 * RECON_PART + 4 * UPD_PART + (1 << 20)) {
        S1 = 2; S2 = 4;
    }

    char* ws = (char*)d_ws;
    size_t off = 0;
    auto alloc = [&](size_t bytes) {
        void* p = ws + off;
        off += (bytes + 255) & ~(size_t)255;
        return p;
    };
    unsigned short* Wn   = (unsigned short*)alloc((size_t)FOUT * FIN * 2); // 16.8 MB
    unsigned char*  WnT8 = (unsigned char*)alloc((size_t)FIN * FOUT);      // 8.4 MB
    unsigned int*   h8u  = (unsigned int*)alloc((size_t)B_DIM * FOUT);     // 4.2 MB
    unsigned int*   rbf  = (unsigned int*)alloc((size_t)B_DIM * FIN * 2);  // 16.8 MB
    unsigned int*   xnb  = (unsigned int*)alloc((size_t)B_DIM * FIN * 2);  // 16.8 MB
    float* h             = (float*)alloc((size_t)B_DIM * FOUT * 4);        // 16.8 MB
    unsigned short* rec  = (unsigned short*)alloc(RECON_PART * S1);
    float* upd           = (float*)alloc(UPD_PART * S2);
    (void)in_sizes; (void)n_in; (void)out_size;

    k_norm_w<<<FOUT, 256, 0, stream>>>(W, Wn);
    k_transpose_fp8<<<dim3(FIN / 32, FOUT / 32), dim3(32, 8), 0, stream>>>(Wn, WnT8);
    k_norm_x<<<B_DIM, 256, 0, stream>>>(x, xnb);
    k_init_h<<<(B_DIM * FOUT) / (256 * 4), 256, 0, stream>>>(h, h8u);

    for (int it = 0; it < NITER; ++it) {
        // recon = h @ Wn : fp8 NT, A=h8 (K=FOUT), B=WnT8 (FIN x FOUT), bf16 partials
        k_gemm_fp8<<<dim3(FIN / 128, B_DIM / 128, S1), 256, 0, stream>>>(
            (const unsigned char*)h8u, WnT8, rec, FIN, FOUT, FOUT / S1);
        k_make_ratio<<<B_DIM, 256, 0, stream>>>(rec, S1, xnb, rbf);
        // upd = r @ Wn^T : bf16 NT, A=rbf (K=FIN), B=Wn (FOUT x FIN), fp32 partials
        k_gemm_nt<<<dim3(FOUT / 128, B_DIM / 128, S2), 256, 0, stream>>>(
            (const unsigned short*)rbf, Wn, upd, FOUT, FIN, FIN / S2);
        k_update_h<<<B_DIM, 256, 0, stream>>>(h, upd, S2, (it == NITER - 1) ? out : h, h8u);
    }
}